// Round 9
// baseline (79098.059 us; speedup 1.0000x reference)
//
#include <hip/hip_runtime.h>
#include <cstdint>
#include <cmath>

// ---------------------------------------------------------------------------
// DDSP decoder on MI355X — inputs/outputs float32 (per reference dtypes).
//   1) precompute: gi_t = f0_t*U + loud_t*V + W  (input GEMM is rank-2+const)
//   2) persistent GRU: 64 blocks x 512 thr (16 cols/block), r16 topology.
//      r19 = r18 (pipelined poll, post-FMA drain) + REGISTER LIVENESS FIX.
//      r18 failed (absmax 468): after breaking from the poll loop with a
//      dead load in flight, A/B were dead in the compiler's liveness model,
//      so their VGPRs were reused for FMA temporaries; the late-landing
//      load clobbered live state (s_waitcnt isn't modeled -> liveness
//      across an un-drained load is invisible; rule #18's cousin).
//      Fix: (a) asm keep-alive of A,B AFTER the post-FMA vmcnt(0) drain
//      pins their registers until the load has landed; (b) sched_barrier(0)
//      BEFORE the drain pins the FMA block above it (it must hide the
//      drain, not sink below it). r17's drain-at-loop-exit was correct but
//      paid ~RT/2 on the critical path every step — r19 keeps the drain
//      hidden under the 384cy FMA block at zero cost.
//      Exchange protocol unchanged from r16: dense 8KB set, block publishes
//      its 16x8B [tag,h] pairs = one 128B line in ONE wave instruction;
//      thread polls ONE dwordx4 = 2 pairs from the same producer store;
//      per-wave parallel gates on i==0, lds_hout gather, barrier B,
//      wave-0 publish. Numerics: identical FMA order, butterfly, gates ->
//      bit-identical output.
//      History: r5 fences; r6 all-poll-all; r7 master-broadcast; r8/r9 fused
//      tagged quads; r10 agent scope; r11 VGPR weights; r12 spread+atomic;
//      r13 dense+atomic = line-sharing regression; r14 exclusive-line
//      packets; r15 pipelined poll null (masked); r16 fat-block topology
//      (63ms best); r17 gate-serialize + exit-drain = regression; r18
//      post-FMA drain = register-reuse race (absmax 468).
//   3) 3x (64x64-tile GEMM bf16-in/f32-acc/bf16-out + bias) + LN+ReLU.
//   4) heads: per-t block; amp/harm/noise projections, exp_sigmoid, normalize.
// ---------------------------------------------------------------------------

#define T_STEPS 32768
#define H_DIM   1024
#define H3      3072
#define NHARM   100
#define NNOISE  65
#define GRU_NB  64
#define GRU_THR 512
#define GRU_CPB 16     // columns (h outputs) per block

// slots layout: 2 sets (step parity) x 1024 pairs x 8B (dense).
// pair j (= global col j) at u32 offset j*2: [tag, f32 h_j].
// block b owns pairs [16b, 16b+16) = exactly one 128B line.
#define SLOT_SET_U32 2048   // 1024 * 2 u32 = 8 KB per set

typedef unsigned short u16;
typedef unsigned uv4 __attribute__((ext_vector_type(4)));
typedef unsigned uv2 __attribute__((ext_vector_type(2)));

__device__ __forceinline__ float b2f(u16 u) {
  union { unsigned u; float f; } x; x.u = ((unsigned)u) << 16; return x.f;
}
__device__ __forceinline__ u16 f2b(float f) {
  unsigned v = __float_as_uint(f);
  unsigned r = (v + 0x7FFFu + ((v >> 16) & 1u)) >> 16;  // RNE
  return (u16)r;
}
__device__ __forceinline__ float sigm(float x) { return 1.0f / (1.0f + expf(-x)); }
__device__ __forceinline__ float exp_sig(float x) {
  // 2.0 * sigmoid(x)^ln(10) + 1e-7
  float s = sigm(x);
  return 2.0f * expf(2.302585093f * logf(s)) + 1e-7f;
}

// Pipelined poll primitives: issue WITHOUT waiting; caller manages depth.
__device__ __forceinline__ void poll_issue1(const unsigned* p, uv4& a) {
  asm volatile("global_load_dwordx4 %0, %1, off sc1"
               : "=v"(a) : "v"(p) : "memory");
}
__device__ __forceinline__ void wait_vm1() {
  asm volatile("s_waitcnt vmcnt(1)" ::: "memory");
  __builtin_amdgcn_sched_barrier(0);   // rule #18: pin the following VALU
}
__device__ __forceinline__ void wait_vm0_pinned() {
  __builtin_amdgcn_sched_barrier(0);   // keep the FMA block ABOVE the drain
  asm volatile("s_waitcnt vmcnt(0)" ::: "memory");
  __builtin_amdgcn_sched_barrier(0);
}
// 8B pair publish: [tag, h] by one lane; 16 lanes of one wave instruction
// cover the block's whole 128B line -> ONE line transaction.
__device__ __forceinline__ void publish_x2(unsigned* p, unsigned t, float h) {
  uv2 v; v.x = t; v.y = __float_as_uint(h);
  asm volatile("global_store_dwordx2 %0, %1, off sc1"
               :: "v"(p), "v"(v) : "memory");
}

// ---------------------------------------------------------------------------
// 1) U[j] = sum_h Win[0,h]*Wi[h,j]; V[j] = sum_h Win[1,h]*Wi[h,j];
//    W[j] = sum_h bin[h]*Wi[h,j].  Blocks 12..15: init the 1024 pairs.
//    (plain stores: end-of-kernel release makes them device-visible)
// ---------------------------------------------------------------------------
__global__ __launch_bounds__(256) void ddsp_precompute(
    const float* __restrict__ Win, const float* __restrict__ bin,
    const float* __restrict__ Wi, const float* __restrict__ h0,
    float* __restrict__ U, float* __restrict__ V, float* __restrict__ Wc,
    unsigned* __restrict__ slots)
{
  const int gid = blockIdx.x * 256 + threadIdx.x;
  if (blockIdx.x < 12) {
    const int j = gid;  // 0..3071
    float su = 0.f, sv = 0.f, sw = 0.f;
    for (int h = 0; h < H_DIM; ++h) {
      const float wv = Wi[h * H3 + j];        // lanes j consecutive -> coalesced
      su = fmaf(Win[h], wv, su);
      sv = fmaf(Win[H_DIM + h], wv, sv);
      sw = fmaf(bin[h], wv, sw);
    }
    U[j] = su; V[j] = sv; Wc[j] = sw;
  } else {
    const int idx = gid - 12 * 256;           // 0..1023 = pair/col index
    unsigned* p0 = slots + (size_t)idx * 2;                 // parity-0 set
    unsigned* p1 = slots + SLOT_SET_U32 + (size_t)idx * 2;  // parity-1 set
    p0[0] = 0u;                               // tag 0 == step 0 valid
    p0[1] = __float_as_uint(h0[idx]);
    p1[0] = 0u;                               // even != any odd tag
    p1[1] = 0u;
  }
}

// ---------------------------------------------------------------------------
// 2) persistent GRU.  64 blocks x 512 thr.  thread = (jl = tid>>5 col 0..15,
//    i = tid&31 k-chunk).  Weights staged per-gate via a 64KB LDS chunk,
//    then kept in VGPRs (rotated order -> static indices).
//    Per step: 2-deep pipelined poll of ONE dwordx4/thread -> parity LDS;
//    barrier A; 8 ds_read_b128 + 96 FMA; post-FMA vmcnt(0) drain (hidden
//    under the FMA block; A/B kept alive past it); butterfly; gates on
//    i==0 of each wave (parallel) -> lds_hout; barrier B; wave-0 lanes
//    0..15 publish the block's line in ONE instruction; hall store after.
// ---------------------------------------------------------------------------
__device__ __forceinline__ void stage_gate(
    float4 (&dst)[8], const float* __restrict__ Wh, float* wg_lds,
    int g, int tid, int i, int jl, int bx)
{
  __syncthreads();   // previous chunk's readers done
  for (int pass = 0; pass < 32; ++pass) {
    const int k = pass * 32 + (tid >> 4);
    const int c = tid & 15;
    wg_lds[c * H_DIM + k] = Wh[(size_t)k * H3 + g * H_DIM + bx * GRU_CPB + c];
  }
  __syncthreads();
  const int kbase = i << 5;
#pragma unroll
  for (int it = 0; it < 8; ++it) {
    const int kk = kbase + (((it + i) & 7) << 2);
    dst[it] = *(const float4*)(wg_lds + jl * H_DIM + kk);
  }
}

__global__ __launch_bounds__(512, 1) void ddsp_gru(
    const float* __restrict__ f0, const float* __restrict__ loud,
    const float* __restrict__ Wh, const float* __restrict__ bh,
    const float* __restrict__ U, const float* __restrict__ V,
    const float* __restrict__ Wc,
    unsigned* __restrict__ slots, u16* __restrict__ hall)
{
  __shared__ float wg_lds[GRU_CPB * H_DIM];    // 64 KB per-gate staging
  __shared__ float lds_h[2][H_DIM];            // 8 KB, step-parity buffers
  __shared__ float lds_hout[GRU_CPB];
  const int tid = threadIdx.x;
  const int i  = tid & 31;
  const int jl = tid >> 5;                     // 0..15
  const int jg = blockIdx.x * GRU_CPB + jl;

  float ur = 0.f, uz = 0.f, un = 0.f, vr = 0.f, vz = 0.f, vn = 0.f;
  float wr = 0.f, wz = 0.f, wn = 0.f, bhr = 0.f, bhz = 0.f, bhn = 0.f;
  if (i == 0) {
    ur = U[jg]; uz = U[jg + 1024]; un = U[jg + 2048];
    vr = V[jg]; vz = V[jg + 1024]; vn = V[jg + 2048];
    wr = Wc[jg]; wz = Wc[jg + 1024]; wn = Wc[jg + 2048];
    bhr = bh[jg]; bhz = bh[jg + 1024]; bhn = bh[jg + 2048];
  }

  // Weights -> VGPRs (per-gate LDS chunks; same values & rotated order as
  // r11-r18 -> bit-identical dot products). Static indices (rule #20).
  float4 wr4[8], wz4[8], wn4[8];
  stage_gate(wr4, Wh, wg_lds, 0, tid, i, jl, blockIdx.x);
  stage_gate(wz4, Wh, wg_lds, 1, tid, i, jl, blockIdx.x);
  stage_gate(wn4, Wh, wg_lds, 2, tid, i, jl, blockIdx.x);

  const int kbase = i << 5;  // i*32

  for (int t = 0; t < T_STEPS; ++t) {
    const unsigned tag = (unsigned)t;
    const int par = t & 1;
    const unsigned* slot_rd = slots + (size_t)par * SLOT_SET_U32;
    unsigned*       slot_wr = slots + (size_t)(par ^ 1) * SLOT_SET_U32;

    // prefetch scalar inputs (issued BEFORE the poll loads: in-order vmcnt
    // retirement keeps "vmcnt(1) => older poll load landed" valid).
    const float fv = f0[t];
    const float lv = loud[t];

    // 2-deep pipelined poll: thread tid owns pairs 2tid, 2tid+1 (16B, one
    // line, both written by the SAME producer instruction). tag==t
    // validates each pair. vmcnt(1) = the OLDER poll load has landed.
    // The dead in-flight load drains after the FMA loop; A/B stay pinned
    // (keep-alive below) so their VGPRs cannot be reused before the drain.
    uv4 A, B;
    {
      const unsigned* p = slot_rd + (size_t)tid * 4;  // byte offset 16*tid
      float2 hq;
      poll_issue1(p, A);
      poll_issue1(p, B);
      for (;;) {
        wait_vm1();                      // A landed (B in flight)
        if (A.x == tag && A.z == tag) {
          hq.x = __uint_as_float(A.y); hq.y = __uint_as_float(A.w);
          break;
        }
        poll_issue1(p, A);               // reissue A (now newest)
        wait_vm1();                      // B landed (A' in flight)
        if (B.x == tag && B.z == tag) {
          hq.x = __uint_as_float(B.y); hq.y = __uint_as_float(B.w);
          break;
        }
        poll_issue1(p, B);               // reissue B
      }
      *(float2*)(&lds_h[par][tid * 2]) = hq;
    }
    __syncthreads();  // barrier A (parity dbuf removes WAR on lds_h)

    // h_prev for this col early (LDS broadcast); hides under the FMA loop.
    const float hp = lds_h[par][jg];

    float a0 = 0.f, a1 = 0.f, a2 = 0.f;
#pragma unroll
    for (int it = 0; it < 8; ++it) {
      const int kk = kbase + (((it + i) & 7) << 2);  // rotation spreads banks
      const float4 h4 = *(const float4*)(&lds_h[par][kk]);
      a0 = fmaf(wr4[it].x, h4.x, a0); a0 = fmaf(wr4[it].y, h4.y, a0);
      a0 = fmaf(wr4[it].z, h4.z, a0); a0 = fmaf(wr4[it].w, h4.w, a0);
      a1 = fmaf(wz4[it].x, h4.x, a1); a1 = fmaf(wz4[it].y, h4.y, a1);
      a1 = fmaf(wz4[it].z, h4.z, a1); a1 = fmaf(wz4[it].w, h4.w, a1);
      a2 = fmaf(wn4[it].x, h4.x, a2); a2 = fmaf(wn4[it].y, h4.y, a2);
      a2 = fmaf(wn4[it].z, h4.z, a2); a2 = fmaf(wn4[it].w, h4.w, a2);
    }
    // Drain the dead poll load. It landed during the 384cy FMA block above
    // (pinned above the wait by sched_barrier), so this is ~free. The
    // keep-alive AFTER the wait extends A/B's live ranges past the drain —
    // the allocator cannot hand their VGPRs to the FMA block (r18's race).
    wait_vm0_pinned();
    asm volatile("" :: "v"(A), "v"(B));  // liveness pin (no code emitted)

    // butterfly reduce over the 32-lane group
#pragma unroll
    for (int m = 1; m < 32; m <<= 1) {
      a0 += __shfl_xor(a0, m);
      a1 += __shfl_xor(a1, m);
      a2 += __shfl_xor(a2, m);
    }
    float hn = 0.f;
    if (i == 0) {
      const float gir = fmaf(fv, ur, fmaf(lv, vr, wr));
      const float giz = fmaf(fv, uz, fmaf(lv, vz, wz));
      const float gin = fmaf(fv, un, fmaf(lv, vn, wn));
      const float r = sigm(gir + a0 + bhr);
      const float z = sigm(giz + a1 + bhz);
      const float n = tanhf(fmaf(r, a2 + bhn, gin));  // b_h[n] inside r*( )
      hn = (1.0f - z) * n + z * hp;
      lds_hout[jl] = hn;
    }
    __syncthreads();  // barrier B: gather the block's 16 cols for publish

    if (tid < GRU_CPB) {
      // ONE wave instruction: 16 lanes x 8B = the block's whole 128B line.
      publish_x2(slot_wr + (size_t)(blockIdx.x * GRU_CPB + tid) * 2,
                 (unsigned)(t + 1), lds_hout[tid]);
    }
    if (i == 0) {
      // history store off the critical path (ack drains during next poll)
      hall[(size_t)t * H_DIM + jg] = f2b(hn);
    }
  }
}

// ---------------------------------------------------------------------------
// 3a) Y[T,1024](bf16) = X[T,1024](bf16) @ W[1024,1024](f32) + bias(f32)
//     64x64 tile, 256 thr, 4x4 micro-tile, K-step 16, f32 accumulate.
// ---------------------------------------------------------------------------
__global__ __launch_bounds__(256) void ddsp_gemm_bias(
    const u16* __restrict__ X, const float* __restrict__ Wt,
    const float* __restrict__ bias, u16* __restrict__ Y)
{
  __shared__ float As[16][64];  // transposed A tile: As[kk][m]
  __shared__ float Bs[16][64];
  const int tid = threadIdx.x;
  const int R0 = blockIdx.x * 64;
  const int N0 = blockIdx.y * 64;
  const int tx = tid & 15, ty = tid >> 4;
  const int am = tid >> 2, ak = (tid & 3) * 4;   // A staging
  const int bk = tid >> 4, bn = (tid & 15) * 4;  // B staging
  float acc[4][4] = {};

  for (int k0 = 0; k0 < H_DIM; k0 += 16) {
    const ushort4 a4 = *(const ushort4*)(X + (size_t)(R0 + am) * H_DIM + k0 + ak);
    const float4 b4 = *(const float4*)(Wt + (size_t)(k0 + bk) * H_DIM + N0 + bn);
    As[ak + 0][am] = b2f(a4.x); As[ak + 1][am] = b2f(a4.y);
    As[ak + 2][am] = b2f(a4.z); As[ak + 3][am] = b2f(a4.w);
    *(float4*)&Bs[bk][bn] = b4;
    __syncthreads();
#pragma unroll
    for (int kk = 0; kk < 16; ++kk) {
      const float4 av = *(const float4*)&As[kk][ty * 4];
      const float4 bv = *(const float4*)&Bs[kk][tx * 4];
      const float a[4] = {av.x, av.y, av.z, av.w};
      const float b[4] = {bv.x, bv.y, bv.z, bv.w};
#pragma unroll
      for (int mi = 0; mi < 4; ++mi)
#pragma unroll
        for (int ni = 0; ni < 4; ++ni)
          acc[mi][ni] = fmaf(a[mi], b[ni], acc[mi][ni]);
    }
    __syncthreads();
  }
  const float4 bv4 = *(const float4*)(bias + N0 + tx * 4);
#pragma unroll
  for (int mi = 0; mi < 4; ++mi) {
    ushort4 st;
    st.x = f2b(acc[mi][0] + bv4.x);
    st.y = f2b(acc[mi][1] + bv4.y);
    st.z = f2b(acc[mi][2] + bv4.z);
    st.w = f2b(acc[mi][3] + bv4.w);
    *(ushort4*)(Y + (size_t)(R0 + ty * 4 + mi) * H_DIM + N0 + tx * 4) = st;
  }
}

// ---------------------------------------------------------------------------
// 3b) in-place LayerNorm + ReLU over bf16 rows of Y (block = row).
// ---------------------------------------------------------------------------
__global__ __launch_bounds__(256) void ddsp_ln_relu(
    u16* __restrict__ Y, const float* __restrict__ scale, const float* __restrict__ bias)
{
  __shared__ float wsum[4], wsq[4];
  const int row = blockIdx.x, tid = threadIdx.x;
  const ushort4 r4 = *(const ushort4*)(Y + (size_t)row * H_DIM + tid * 4);
  float x[4] = {b2f(r4.x), b2f(r4.y), b2f(r4.z), b2f(r4.w)};
  float s = x[0] + x[1] + x[2] + x[3];
  float q = x[0] * x[0] + x[1] * x[1] + x[2] * x[2] + x[3] * x[3];
#pragma unroll
  for (int off = 32; off >= 1; off >>= 1) {
    s += __shfl_down(s, off);
    q += __shfl_down(q, off);
  }
  if ((tid & 63) == 0) { wsum[tid >> 6] = s; wsq[tid >> 6] = q; }
  __syncthreads();
  const float ts = wsum[0] + wsum[1] + wsum[2] + wsum[3];
  const float tq = wsq[0] + wsq[1] + wsq[2] + wsq[3];
  const float mu = ts * (1.0f / H_DIM);
  const float var = tq * (1.0f / H_DIM) - mu * mu;
  const float rstd = rsqrtf(fmaxf(var, 0.f) + 1e-6f);
  const float4 sc = *(const float4*)(scale + tid * 4);
  const float4 bi = *(const float4*)(bias + tid * 4);
  ushort4 st;
  st.x = f2b(fmaxf((x[0] - mu) * rstd * sc.x + bi.x, 0.f));
  st.y = f2b(fmaxf((x[1] - mu) * rstd * sc.y + bi.y, 0.f));
  st.z = f2b(fmaxf((x[2] - mu) * rstd * sc.z + bi.z, 0.f));
  st.w = f2b(fmaxf((x[3] - mu) * rstd * sc.w + bi.w, 0.f));
  *(ushort4*)(Y + (size_t)row * H_DIM + tid * 4) = st;
}

// ---------------------------------------------------------------------------
// 4) heads: block = timestep. threads 0..99 harm, 100..164 noise, 165 amp.
//    Hf is bf16; weights/bias/output f32.
// ---------------------------------------------------------------------------
__global__ __launch_bounds__(256) void ddsp_heads(
    const u16* __restrict__ Hf,
    const float* __restrict__ aW, const float* __restrict__ ab,
    const float* __restrict__ hW, const float* __restrict__ hb,
    const float* __restrict__ nW, const float* __restrict__ nb,
    float* __restrict__ out)
{
  __shared__ float lh[H_DIM];
  __shared__ float se[128];
  __shared__ float sred[2];  // [0]=amp, [1]=harm sum
  const int t = blockIdx.x, tid = threadIdx.x;
  const ushort4 h4 = *(const ushort4*)(Hf + (size_t)t * H_DIM + tid * 4);
  lh[tid * 4 + 0] = b2f(h4.x); lh[tid * 4 + 1] = b2f(h4.y);
  lh[tid * 4 + 2] = b2f(h4.z); lh[tid * 4 + 3] = b2f(h4.w);
  __syncthreads();

  if (tid < NHARM) {
    float acc = 0.f;
    for (int k = 0; k < H_DIM; k += 4) {
      const float4 hv = *(const float4*)(lh + k);
      acc = fmaf(hv.x, hW[(k + 0) * NHARM + tid], acc);
      acc = fmaf(hv.y, hW[(k + 1) * NHARM + tid], acc);
      acc = fmaf(hv.z, hW[(k + 2) * NHARM + tid], acc);
      acc = fmaf(hv.w, hW[(k + 3) * NHARM + tid], acc);
    }
    se[tid] = exp_sig(acc + hb[tid]);
  } else if (tid < NHARM + NNOISE) {
    const int n = tid - NHARM;
    float acc = 0.f;
    for (int k = 0; k < H_DIM; k += 4) {
      const float4 hv = *(const float4*)(lh + k);
      acc = fmaf(hv.x, nW[(k + 0) * NNOISE + n], acc);
      acc = fmaf(hv.y, nW[(k + 1) * NNOISE + n], acc);
      acc = fmaf(hv.z, nW[(k + 2) * NNOISE + n], acc);
      acc = fmaf(hv.w, nW[(k + 3) * NNOISE + n], acc);
    }
    out[(size_t)T_STEPS * NHARM + (size_t)t * NNOISE + n] = acc + nb[n];
  } else if (tid == NHARM + NNOISE) {
    float acc = 0.f;
    for (int k = 0; k < H_DIM; k += 4) {
      const float4 hv = *(const float4*)(lh + k);
      acc = fmaf(hv.x, aW[k + 0], acc);
      acc = fmaf(hv.y, aW[k + 1], acc);
      acc = fmaf(hv.z, aW[k + 2], acc);
      acc = fmaf(hv.w, aW[k + 3], acc);
    }
    sred[0] = exp_sig(acc + ab[0]);
  }
  if (tid >= NHARM && tid < 128) se[tid] = 0.f;  // pad for reduce
  __syncthreads();
  if (tid < 64) {
    float s2 = se[tid] + se[tid + 64];
#pragma unroll
    for (int off = 32; off >= 1; off >>= 1) s2 += __shfl_down(s2, off);
    if (tid == 0) sred[1] = s2;
  }
  __syncthreads();
  if (tid < NHARM) {
    out[(size_t)t * NHARM + tid] = sred[0] * se[tid] / (sred[1] + 1e-8f);
  }
}

// ---------------------------------------------------------------------------
extern "C" void kernel_launch(void* const* d_in, const int* in_sizes, int n_in,
                              void* d_out, int out_size, void* d_ws, size_t ws_size,
                              hipStream_t stream)
{
  (void)in_sizes; (void)n_in; (void)out_size;
  const float* f0   = (const float*)d_in[0];
  const float* loud = (const float*)d_in[1];
  const float* Win  = (const float*)d_in[2];
  const float* bin  = (const float*)d_in[3];
  const float* Wi   = (const float*)d_in[4];
  const float* Wh   = (const float*)d_in[5];
  const float* bh   = (const float*)d_in[6];
  const float* h0   = (const float*)d_in[7];
  const float* mlpW = (const float*)d_in[8];
  const float* mlpb = (const float*)d_in[9];
  const float* lnS  = (const float*)d_in[10];
  const float* lnB  = (const float*)d_in[11];
  const float* aW   = (const float*)d_in[12];
  const float* ab   = (const float*)d_in[13];
  const float* hW   = (const float*)d_in[14];
  const float* hb   = (const float*)d_in[15];
  const float* nW   = (const float*)d_in[16];
  const float* nb   = (const float*)d_in[17];
  float* out = (float*)d_out;

  char* ws = (char*)d_ws;
  float*    U     = (float*)(ws);                    // 3072 f32
  float*    V     = (float*)(ws + 12288);            // 3072 f32
  float*    Wc    = (float*)(ws + 24576);            // 3072 f32
  u16* bufA = (u16*)(ws + 53248);                               // [T,H] bf16
  u16* bufB = (u16*)(ws + 53248 + (size_t)T_STEPS * H_DIM * 2); // [T,H] bf16
  // slots (2 x 8KB) overlap bufB: slots are dead before GEMM1 writes bufB.
  unsigned* slots = (unsigned*)bufB;                 // 128B-aligned

  const size_t needed = 53248 + 2 * (size_t)T_STEPS * H_DIM * 2;  // ~134.3 MB
  if (ws_size < needed) {
    // Workspace too small: do nothing -> bench reports absmax == max|ref|.
    return;
  }

  ddsp_precompute<<<16, 256, 0, stream>>>(Win, bin, Wi, h0, U, V, Wc, slots);
  ddsp_gru<<<GRU_NB, GRU_THR, 0, stream>>>(f0, loud, Wh, bh, U, V, Wc, slots, bufA);

  dim3 gg(T_STEPS / 64, H_DIM / 64);
  ddsp_gemm_bias<<<gg, 256, 0, stream>>>(bufA, mlpW, mlpb, bufB);
  ddsp_ln_relu<<<T_STEPS, 256, 0, stream>>>(bufB, lnS, lnB);
  ddsp_gemm_bias<<<gg, 256, 0, stream>>>(bufB, mlpW + (size_t)H_DIM * H_DIM, mlpb + H_DIM, bufA);
  ddsp_ln_relu<<<T_STEPS, 256, 0, stream>>>(bufA, lnS + H_DIM, lnB + H_DIM);
  ddsp_gemm_bias<<<gg, 256, 0, stream>>>(bufA, mlpW + 2 * (size_t)H_DIM * H_DIM, mlpb + 2 * H_DIM, bufB);
  ddsp_ln_relu<<<T_STEPS, 256, 0, stream>>>(bufB, lnS + 2 * H_DIM, lnB + 2 * H_DIM);

  ddsp_heads<<<T_STEPS, 256, 0, stream>>>(bufB, aW, ab, hW, hb, nW, nb, out);
}

// Round 10
// 69218.311 us; speedup vs baseline: 1.1427x; 1.1427x over previous
//
#include <hip/hip_runtime.h>
#include <cstdint>
#include <cmath>

// ---------------------------------------------------------------------------
// DDSP decoder on MI355X — inputs/outputs float32 (per reference dtypes).
//   1) precompute: gi_t = f0_t*U + loud_t*V + W  (input GEMM is rank-2+const)
//   2) persistent GRU: 64 blocks x 512 thr (16 cols/block) — r16 structure,
//      which is the measured best (1.93us/step). r20 = r16 + coalesced hall
//      store (wave-0 lanes 0..15 write 32B contiguous after the publish,
//      replacing 8 scattered 2-active-lane stores; same values, same
//      addresses -> bit-identical).
//      Exchange protocol (the settled design after r11-r19):
//        * dense 8KB slot set, parity double-buffered; pair j at j*8B =
//          [tag, f32 h_j]; block b owns pairs [16b,16b+16) = ONE 128B line.
//        * publish: ONE wave instruction (wave-0 lanes 0..15, 16x8B) per
//          block = one line transaction, one stale->fresh transition
//          (r13 lesson: exactly one producer INSTRUCTION per line).
//        * poll: thread reads ONE dwordx4 = 2 pairs, both from the same
//          producer store (no partial arrival); wave covers 1KB contiguous;
//          ~4K line transactions/grid-round (r16: 16x fewer than r14).
//        * simple issue->vmcnt(0)->check poll. Pipelined polling (r15, r19)
//          is NULL: FETCH byte-identical, dur equal-to-worse — rounds are
//          paced by producer publish visibility, not consumer wait shape.
//        * per-wave parallel gates on i==0 (r17's wave-0 consolidation
//          serialized the transcendentals onto the critical path: regression)
//      History: r5 fences; r6 all-poll-all; r7 master-broadcast; r8/r9 fused
//      tagged quads; r10 agent scope; r11 VGPR weights; r12 spread+atomic;
//      r13 dense+atomic line-sharing regression; r14 exclusive-line packets;
//      r15 pipelined poll null; r16 fat-block topology (best: 63ms);
//      r17 gate-serialize regression; r18 register-reuse race (absmax 468);
//      r19 pinned pipelined poll = clean null (FETCH identical, dur ~=).
//      The remaining per-step cost is the publish->IC-visibility->detect RT
//      chain + 2 block barriers — the protocol floor on this fabric.
//   3) 3x (64x64-tile GEMM bf16-in/f32-acc/bf16-out + bias) + LN+ReLU.
//   4) heads: per-t block; amp/harm/noise projections, exp_sigmoid, normalize.
// ---------------------------------------------------------------------------

#define T_STEPS 32768
#define H_DIM   1024
#define H3      3072
#define NHARM   100
#define NNOISE  65
#define GRU_NB  64
#define GRU_THR 512
#define GRU_CPB 16     // columns (h outputs) per block

// slots layout: 2 sets (step parity) x 1024 pairs x 8B (dense).
// pair j (= global col j) at u32 offset j*2: [tag, f32 h_j].
// block b owns pairs [16b, 16b+16) = exactly one 128B line.
#define SLOT_SET_U32 2048   // 1024 * 2 u32 = 8 KB per set

typedef unsigned short u16;
typedef unsigned uv4 __attribute__((ext_vector_type(4)));
typedef unsigned uv2 __attribute__((ext_vector_type(2)));

__device__ __forceinline__ float b2f(u16 u) {
  union { unsigned u; float f; } x; x.u = ((unsigned)u) << 16; return x.f;
}
__device__ __forceinline__ u16 f2b(float f) {
  unsigned v = __float_as_uint(f);
  unsigned r = (v + 0x7FFFu + ((v >> 16) & 1u)) >> 16;  // RNE
  return (u16)r;
}
__device__ __forceinline__ float sigm(float x) { return 1.0f / (1.0f + expf(-x)); }
__device__ __forceinline__ float exp_sig(float x) {
  // 2.0 * sigmoid(x)^ln(10) + 1e-7
  float s = sigm(x);
  return 2.0f * expf(2.302585093f * logf(s)) + 1e-7f;
}

// One dense poll read: dwordx4 = 2 tagged [tag,h] pairs, agent scope (sc1).
__device__ __forceinline__ void poll_load_1(const unsigned* p, uv4& a) {
  asm volatile("global_load_dwordx4 %0, %1, off sc1\n\t"
               "s_waitcnt vmcnt(0)"
               : "=v"(a) : "v"(p) : "memory");
}
// 8B pair publish: [tag, h] by one lane; 16 lanes of one wave instruction
// cover the block's whole 128B line -> ONE line transaction.
__device__ __forceinline__ void publish_x2(unsigned* p, unsigned t, float h) {
  uv2 v; v.x = t; v.y = __float_as_uint(h);
  asm volatile("global_store_dwordx2 %0, %1, off sc1"
               :: "v"(p), "v"(v) : "memory");
}

// ---------------------------------------------------------------------------
// 1) U[j] = sum_h Win[0,h]*Wi[h,j]; V[j] = sum_h Win[1,h]*Wi[h,j];
//    W[j] = sum_h bin[h]*Wi[h,j].  Blocks 12..15: init the 1024 pairs.
//    (plain stores: end-of-kernel release makes them device-visible)
// ---------------------------------------------------------------------------
__global__ __launch_bounds__(256) void ddsp_precompute(
    const float* __restrict__ Win, const float* __restrict__ bin,
    const float* __restrict__ Wi, const float* __restrict__ h0,
    float* __restrict__ U, float* __restrict__ V, float* __restrict__ Wc,
    unsigned* __restrict__ slots)
{
  const int gid = blockIdx.x * 256 + threadIdx.x;
  if (blockIdx.x < 12) {
    const int j = gid;  // 0..3071
    float su = 0.f, sv = 0.f, sw = 0.f;
    for (int h = 0; h < H_DIM; ++h) {
      const float wv = Wi[h * H3 + j];        // lanes j consecutive -> coalesced
      su = fmaf(Win[h], wv, su);
      sv = fmaf(Win[H_DIM + h], wv, sv);
      sw = fmaf(bin[h], wv, sw);
    }
    U[j] = su; V[j] = sv; Wc[j] = sw;
  } else {
    const int idx = gid - 12 * 256;           // 0..1023 = pair/col index
    unsigned* p0 = slots + (size_t)idx * 2;                 // parity-0 set
    unsigned* p1 = slots + SLOT_SET_U32 + (size_t)idx * 2;  // parity-1 set
    p0[0] = 0u;                               // tag 0 == step 0 valid
    p0[1] = __float_as_uint(h0[idx]);
    p1[0] = 0u;                               // even != any odd tag
    p1[1] = 0u;
  }
}

// ---------------------------------------------------------------------------
// 2) persistent GRU.  64 blocks x 512 thr.  thread = (jl = tid>>5 col 0..15,
//    i = tid&31 k-chunk).  Weights staged per-gate via a 64KB LDS chunk,
//    then kept in VGPRs (rotated order -> static indices).
//    Per step: thread tid polls ONE dwordx4 (pairs 2tid,2tid+1, both from
//    one producer store), writes float2 of h to the parity LDS buffer;
//    barrier A; 8 ds_read_b128 + 96 FMA; butterfly; gates on i==0 of each
//    wave (parallel) -> lds_hout; barrier B; wave-0 lanes 0..15 publish the
//    block's line in ONE instruction and then write the hall history slice
//    (32B contiguous; drains during the next poll).
// ---------------------------------------------------------------------------
__device__ __forceinline__ void stage_gate(
    float4 (&dst)[8], const float* __restrict__ Wh, float* wg_lds,
    int g, int tid, int i, int jl, int bx)
{
  __syncthreads();   // previous chunk's readers done
  for (int pass = 0; pass < 32; ++pass) {
    const int k = pass * 32 + (tid >> 4);
    const int c = tid & 15;
    wg_lds[c * H_DIM + k] = Wh[(size_t)k * H3 + g * H_DIM + bx * GRU_CPB + c];
  }
  __syncthreads();
  const int kbase = i << 5;
#pragma unroll
  for (int it = 0; it < 8; ++it) {
    const int kk = kbase + (((it + i) & 7) << 2);
    dst[it] = *(const float4*)(wg_lds + jl * H_DIM + kk);
  }
}

__global__ __launch_bounds__(512, 1) void ddsp_gru(
    const float* __restrict__ f0, const float* __restrict__ loud,
    const float* __restrict__ Wh, const float* __restrict__ bh,
    const float* __restrict__ U, const float* __restrict__ V,
    const float* __restrict__ Wc,
    unsigned* __restrict__ slots, u16* __restrict__ hall)
{
  __shared__ float wg_lds[GRU_CPB * H_DIM];    // 64 KB per-gate staging
  __shared__ float lds_h[2][H_DIM];            // 8 KB, step-parity buffers
  __shared__ float lds_hout[GRU_CPB];
  const int tid = threadIdx.x;
  const int i  = tid & 31;
  const int jl = tid >> 5;                     // 0..15
  const int jg = blockIdx.x * GRU_CPB + jl;

  float ur = 0.f, uz = 0.f, un = 0.f, vr = 0.f, vz = 0.f, vn = 0.f;
  float wr = 0.f, wz = 0.f, wn = 0.f, bhr = 0.f, bhz = 0.f, bhn = 0.f;
  if (i == 0) {
    ur = U[jg]; uz = U[jg + 1024]; un = U[jg + 2048];
    vr = V[jg]; vz = V[jg + 1024]; vn = V[jg + 2048];
    wr = Wc[jg]; wz = Wc[jg + 1024]; wn = Wc[jg + 2048];
    bhr = bh[jg]; bhz = bh[jg + 1024]; bhn = bh[jg + 2048];
  }

  // Weights -> VGPRs (per-gate LDS chunks; same values & rotated order as
  // r11-r19 -> bit-identical dot products). Static indices (rule #20).
  float4 wr4[8], wz4[8], wn4[8];
  stage_gate(wr4, Wh, wg_lds, 0, tid, i, jl, blockIdx.x);
  stage_gate(wz4, Wh, wg_lds, 1, tid, i, jl, blockIdx.x);
  stage_gate(wn4, Wh, wg_lds, 2, tid, i, jl, blockIdx.x);

  const int kbase = i << 5;  // i*32

  for (int t = 0; t < T_STEPS; ++t) {
    const unsigned tag = (unsigned)t;
    const int par = t & 1;
    const unsigned* slot_rd = slots + (size_t)par * SLOT_SET_U32;
    unsigned*       slot_wr = slots + (size_t)(par ^ 1) * SLOT_SET_U32;

    // prefetch scalar inputs; latency hides under the poll's vmcnt(0)
    const float fv = f0[t];
    const float lv = loud[t];

    // dense poll: thread tid owns pairs 2tid, 2tid+1 (16B, one line, both
    // written by the SAME producer instruction). tag==t validates each pair.
    {
      const unsigned* p = slot_rd + (size_t)tid * 4;  // byte offset 16*tid
      uv4 a;
      do {
        poll_load_1(p, a);
      } while (a.x != tag || a.z != tag);
      float2 hq;
      hq.x = __uint_as_float(a.y); hq.y = __uint_as_float(a.w);
      *(float2*)(&lds_h[par][tid * 2]) = hq;
    }
    __syncthreads();  // barrier A (parity dbuf removes WAR on lds_h)

    // h_prev for this col early (LDS broadcast); hides under the FMA loop.
    const float hp = lds_h[par][jg];

    float a0 = 0.f, a1 = 0.f, a2 = 0.f;
#pragma unroll
    for (int it = 0; it < 8; ++it) {
      const int kk = kbase + (((it + i) & 7) << 2);  // rotation spreads banks
      const float4 h4 = *(const float4*)(&lds_h[par][kk]);
      a0 = fmaf(wr4[it].x, h4.x, a0); a0 = fmaf(wr4[it].y, h4.y, a0);
      a0 = fmaf(wr4[it].z, h4.z, a0); a0 = fmaf(wr4[it].w, h4.w, a0);
      a1 = fmaf(wz4[it].x, h4.x, a1); a1 = fmaf(wz4[it].y, h4.y, a1);
      a1 = fmaf(wz4[it].z, h4.z, a1); a1 = fmaf(wz4[it].w, h4.w, a1);
      a2 = fmaf(wn4[it].x, h4.x, a2); a2 = fmaf(wn4[it].y, h4.y, a2);
      a2 = fmaf(wn4[it].z, h4.z, a2); a2 = fmaf(wn4[it].w, h4.w, a2);
    }
    // butterfly reduce over the 32-lane group
#pragma unroll
    for (int m = 1; m < 32; m <<= 1) {
      a0 += __shfl_xor(a0, m);
      a1 += __shfl_xor(a1, m);
      a2 += __shfl_xor(a2, m);
    }
    float hn = 0.f;
    if (i == 0) {
      const float gir = fmaf(fv, ur, fmaf(lv, vr, wr));
      const float giz = fmaf(fv, uz, fmaf(lv, vz, wz));
      const float gin = fmaf(fv, un, fmaf(lv, vn, wn));
      const float r = sigm(gir + a0 + bhr);
      const float z = sigm(giz + a1 + bhz);
      const float n = tanhf(fmaf(r, a2 + bhn, gin));  // b_h[n] inside r*( )
      hn = (1.0f - z) * n + z * hp;
      lds_hout[jl] = hn;
    }
    __syncthreads();  // barrier B: gather the block's 16 cols for publish

    if (tid < GRU_CPB) {
      // ONE wave instruction: 16 lanes x 8B = the block's whole 128B line.
      const float hv = lds_hout[tid];
      publish_x2(slot_wr + (size_t)(blockIdx.x * GRU_CPB + tid) * 2,
                 (unsigned)(t + 1), hv);
      // hall history: 16 lanes x 2B = 32B contiguous, ONE instruction/
      // transaction (r16 used 8 scattered 2-active-lane stores). Same
      // values/addresses -> bit-identical; drains during the next poll.
      hall[(size_t)t * H_DIM + blockIdx.x * GRU_CPB + tid] = f2b(hv);
    }
  }
}

// ---------------------------------------------------------------------------
// 3a) Y[T,1024](bf16) = X[T,1024](bf16) @ W[1024,1024](f32) + bias(f32)
//     64x64 tile, 256 thr, 4x4 micro-tile, K-step 16, f32 accumulate.
// ---------------------------------------------------------------------------
__global__ __launch_bounds__(256) void ddsp_gemm_bias(
    const u16* __restrict__ X, const float* __restrict__ Wt,
    const float* __restrict__ bias, u16* __restrict__ Y)
{
  __shared__ float As[16][64];  // transposed A tile: As[kk][m]
  __shared__ float Bs[16][64];
  const int tid = threadIdx.x;
  const int R0 = blockIdx.x * 64;
  const int N0 = blockIdx.y * 64;
  const int tx = tid & 15, ty = tid >> 4;
  const int am = tid >> 2, ak = (tid & 3) * 4;   // A staging
  const int bk = tid >> 4, bn = (tid & 15) * 4;  // B staging
  float acc[4][4] = {};

  for (int k0 = 0; k0 < H_DIM; k0 += 16) {
    const ushort4 a4 = *(const ushort4*)(X + (size_t)(R0 + am) * H_DIM + k0 + ak);
    const float4 b4 = *(const float4*)(Wt + (size_t)(k0 + bk) * H_DIM + N0 + bn);
    As[ak + 0][am] = b2f(a4.x); As[ak + 1][am] = b2f(a4.y);
    As[ak + 2][am] = b2f(a4.z); As[ak + 3][am] = b2f(a4.w);
    *(float4*)&Bs[bk][bn] = b4;
    __syncthreads();
#pragma unroll
    for (int kk = 0; kk < 16; ++kk) {
      const float4 av = *(const float4*)&As[kk][ty * 4];
      const float4 bv = *(const float4*)&Bs[kk][tx * 4];
      const float a[4] = {av.x, av.y, av.z, av.w};
      const float b[4] = {bv.x, bv.y, bv.z, bv.w};
#pragma unroll
      for (int mi = 0; mi < 4; ++mi)
#pragma unroll
        for (int ni = 0; ni < 4; ++ni)
          acc[mi][ni] = fmaf(a[mi], b[ni], acc[mi][ni]);
    }
    __syncthreads();
  }
  const float4 bv4 = *(const float4*)(bias + N0 + tx * 4);
#pragma unroll
  for (int mi = 0; mi < 4; ++mi) {
    ushort4 st;
    st.x = f2b(acc[mi][0] + bv4.x);
    st.y = f2b(acc[mi][1] + bv4.y);
    st.z = f2b(acc[mi][2] + bv4.z);
    st.w = f2b(acc[mi][3] + bv4.w);
    *(ushort4*)(Y + (size_t)(R0 + ty * 4 + mi) * H_DIM + N0 + tx * 4) = st;
  }
}

// ---------------------------------------------------------------------------
// 3b) in-place LayerNorm + ReLU over bf16 rows of Y (block = row).
// ---------------------------------------------------------------------------
__global__ __launch_bounds__(256) void ddsp_ln_relu(
    u16* __restrict__ Y, const float* __restrict__ scale, const float* __restrict__ bias)
{
  __shared__ float wsum[4], wsq[4];
  const int row = blockIdx.x, tid = threadIdx.x;
  const ushort4 r4 = *(const ushort4*)(Y + (size_t)row * H_DIM + tid * 4);
  float x[4] = {b2f(r4.x), b2f(r4.y), b2f(r4.z), b2f(r4.w)};
  float s = x[0] + x[1] + x[2] + x[3];
  float q = x[0] * x[0] + x[1] * x[1] + x[2] * x[2] + x[3] * x[3];
#pragma unroll
  for (int off = 32; off >= 1; off >>= 1) {
    s += __shfl_down(s, off);
    q += __shfl_down(q, off);
  }
  if ((tid & 63) == 0) { wsum[tid >> 6] = s; wsq[tid >> 6] = q; }
  __syncthreads();
  const float ts = wsum[0] + wsum[1] + wsum[2] + wsum[3];
  const float tq = wsq[0] + wsq[1] + wsq[2] + wsq[3];
  const float mu = ts * (1.0f / H_DIM);
  const float var = tq * (1.0f / H_DIM) - mu * mu;
  const float rstd = rsqrtf(fmaxf(var, 0.f) + 1e-6f);
  const float4 sc = *(const float4*)(scale + tid * 4);
  const float4 bi = *(const float4*)(bias + tid * 4);
  ushort4 st;
  st.x = f2b(fmaxf((x[0] - mu) * rstd * sc.x + bi.x, 0.f));
  st.y = f2b(fmaxf((x[1] - mu) * rstd * sc.y + bi.y, 0.f));
  st.z = f2b(fmaxf((x[2] - mu) * rstd * sc.z + bi.z, 0.f));
  st.w = f2b(fmaxf((x[3] - mu) * rstd * sc.w + bi.w, 0.f));
  *(ushort4*)(Y + (size_t)row * H_DIM + tid * 4) = st;
}

// ---------------------------------------------------------------------------
// 4) heads: block = timestep. threads 0..99 harm, 100..164 noise, 165 amp.
//    Hf is bf16; weights/bias/output f32.
// ---------------------------------------------------------------------------
__global__ __launch_bounds__(256) void ddsp_heads(
    const u16* __restrict__ Hf,
    const float* __restrict__ aW, const float* __restrict__ ab,
    const float* __restrict__ hW, const float* __restrict__ hb,
    const float* __restrict__ nW, const float* __restrict__ nb,
    float* __restrict__ out)
{
  __shared__ float lh[H_DIM];
  __shared__ float se[128];
  __shared__ float sred[2];  // [0]=amp, [1]=harm sum
  const int t = blockIdx.x, tid = threadIdx.x;
  const ushort4 h4 = *(const ushort4*)(Hf + (size_t)t * H_DIM + tid * 4);
  lh[tid * 4 + 0] = b2f(h4.x); lh[tid * 4 + 1] = b2f(h4.y);
  lh[tid * 4 + 2] = b2f(h4.z); lh[tid * 4 + 3] = b2f(h4.w);
  __syncthreads();

  if (tid < NHARM) {
    float acc = 0.f;
    for (int k = 0; k < H_DIM; k += 4) {
      const float4 hv = *(const float4*)(lh + k);
      acc = fmaf(hv.x, hW[(k + 0) * NHARM + tid], acc);
      acc = fmaf(hv.y, hW[(k + 1) * NHARM + tid], acc);
      acc = fmaf(hv.z, hW[(k + 2) * NHARM + tid], acc);
      acc = fmaf(hv.w, hW[(k + 3) * NHARM + tid], acc);
    }
    se[tid] = exp_sig(acc + hb[tid]);
  } else if (tid < NHARM + NNOISE) {
    const int n = tid - NHARM;
    float acc = 0.f;
    for (int k = 0; k < H_DIM; k += 4) {
      const float4 hv = *(const float4*)(lh + k);
      acc = fmaf(hv.x, nW[(k + 0) * NNOISE + n], acc);
      acc = fmaf(hv.y, nW[(k + 1) * NNOISE + n], acc);
      acc = fmaf(hv.z, nW[(k + 2) * NNOISE + n], acc);
      acc = fmaf(hv.w, nW[(k + 3) * NNOISE + n], acc);
    }
    out[(size_t)T_STEPS * NHARM + (size_t)t * NNOISE + n] = acc + nb[n];
  } else if (tid == NHARM + NNOISE) {
    float acc = 0.f;
    for (int k = 0; k < H_DIM; k += 4) {
      const float4 hv = *(const float4*)(lh + k);
      acc = fmaf(hv.x, aW[k + 0], acc);
      acc = fmaf(hv.y, aW[k + 1], acc);
      acc = fmaf(hv.z, aW[k + 2], acc);
      acc = fmaf(hv.w, aW[k + 3], acc);
    }
    sred[0] = exp_sig(acc + ab[0]);
  }
  if (tid >= NHARM && tid < 128) se[tid] = 0.f;  // pad for reduce
  __syncthreads();
  if (tid < 64) {
    float s2 = se[tid] + se[tid + 64];
#pragma unroll
    for (int off = 32; off >= 1; off >>= 1) s2 += __shfl_down(s2, off);
    if (tid == 0) sred[1] = s2;
  }
  __syncthreads();
  if (tid < NHARM) {
    out[(size_t)t * NHARM + tid] = sred[0] * se[tid] / (sred[1] + 1e-8f);
  }
}

// ---------------------------------------------------------------------------
extern "C" void kernel_launch(void* const* d_in, const int* in_sizes, int n_in,
                              void* d_out, int out_size, void* d_ws, size_t ws_size,
                              hipStream_t stream)
{
  (void)in_sizes; (void)n_in; (void)out_size;
  const float* f0   = (const float*)d_in[0];
  const float* loud = (const float*)d_in[1];
  const float* Win  = (const float*)d_in[2];
  const float* bin  = (const float*)d_in[3];
  const float* Wi   = (const float*)d_in[4];
  const float* Wh   = (const float*)d_in[5];
  const float* bh   = (const float*)d_in[6];
  const float* h0   = (const float*)d_in[7];
  const float* mlpW = (const float*)d_in[8];
  const float* mlpb = (const float*)d_in[9];
  const float* lnS  = (const float*)d_in[10];
  const float* lnB  = (const float*)d_in[11];
  const float* aW   = (const float*)d_in[12];
  const float* ab   = (const float*)d_in[13];
  const float* hW   = (const float*)d_in[14];
  const float* hb   = (const float*)d_in[15];
  const float* nW   = (const float*)d_in[16];
  const float* nb   = (const float*)d_in[17];
  float* out = (float*)d_out;

  char* ws = (char*)d_ws;
  float*    U     = (float*)(ws);                    // 3072 f32
  float*    V     = (float*)(ws + 12288);            // 3072 f32
  float*    Wc    = (float*)(ws + 24576);            // 3072 f32
  u16* bufA = (u16*)(ws + 53248);                               // [T,H] bf16
  u16* bufB = (u16*)(ws + 53248 + (size_t)T_STEPS * H_DIM * 2); // [T,H] bf16
  // slots (2 x 8KB) overlap bufB: slots are dead before GEMM1 writes bufB.
  unsigned* slots = (unsigned*)bufB;                 // 128B-aligned

  const size_t needed = 53248 + 2 * (size_t)T_STEPS * H_DIM * 2;  // ~134.3 MB
  if (ws_size < needed) {
    // Workspace too small: do nothing -> bench reports absmax == max|ref|.
    return;
  }

  ddsp_precompute<<<16, 256, 0, stream>>>(Win, bin, Wi, h0, U, V, Wc, slots);
  ddsp_gru<<<GRU_NB, GRU_THR, 0, stream>>>(f0, loud, Wh, bh, U, V, Wc, slots, bufA);

  dim3 gg(T_STEPS / 64, H_DIM / 64);
  ddsp_gemm_bias<<<gg, 256, 0, stream>>>(bufA, mlpW, mlpb, bufB);
  ddsp_ln_relu<<<T_STEPS, 256, 0, stream>>>(bufB, lnS, lnB);
  ddsp_gemm_bias<<<gg, 256, 0, stream>>>(bufB, mlpW + (size_t)H_DIM * H_DIM, mlpb + H_DIM, bufA);
  ddsp_ln_relu<<<T_STEPS, 256, 0, stream>>>(bufA, lnS + H_DIM, lnB + H_DIM);
  ddsp_gemm_bias<<<gg, 256, 0, stream>>>(bufA, mlpW + 2 * (size_t)H_DIM * H_DIM, mlpb + 2 * H_DIM, bufB);
  ddsp_ln_relu<<<T_STEPS, 256, 0, stream>>>(bufB, lnS + 2 * H_DIM, lnB + 2 * H_DIM);

  ddsp_heads<<<T_STEPS, 256, 0, stream>>>(bufB, aW, ab, hW, hb, nW, nb, out);
}